// Round 1
// baseline (450.379 us; speedup 1.0000x reference)
//
#include <hip/hip_runtime.h>
#include <math.h>

constexpr int D = 128;

// ---------------- preprocessing kernels ----------------

// Detect whether edge_index is int64 (little-endian: odd int32 words zero) or int32.
__global__ void k_detect(const int* __restrict__ ei, int* __restrict__ flag) {
  if (blockIdx.x == 0 && threadIdx.x == 0) {
    int z = 0;
#pragma unroll
    for (int i = 0; i < 8; ++i) z |= ei[2 * i + 1];
    *flag = (z == 0) ? 1 : 0;
  }
}

__global__ void k_zero(float* __restrict__ deg, int* __restrict__ cnt,
                       int* __restrict__ cur, int n) {
  int i = blockIdx.x * blockDim.x + threadIdx.x;
  if (i < n) { deg[i] = 0.f; cnt[i] = 0; cur[i] = 0; }
}

__device__ __forceinline__ void load_edge(const int* __restrict__ ei, int e, int nE,
                                          int m64, int n, int& r, int& c) {
  if (m64) { r = ei[2 * (size_t)e]; c = ei[2 * ((size_t)nE + e)]; }
  else     { r = ei[(size_t)e];     c = ei[(size_t)nE + e]; }
  r = min(max(r, 0), n - 1);
  c = min(max(c, 0), n - 1);
}

__global__ void k_count(const int* __restrict__ ei, const float* __restrict__ w,
                        float* __restrict__ deg, int* __restrict__ cnt,
                        const int* __restrict__ flag, int nE, int n) {
  int e = blockIdx.x * blockDim.x + threadIdx.x;
  if (e >= nE) return;
  int m64 = *flag;
  int r, c;
  load_edge(ei, e, nE, m64, n, r, c);
  atomicAdd(&deg[c], w[e]);
  atomicAdd(&cnt[c], 1);
}

__global__ void k_dinv(const float* __restrict__ deg, float* __restrict__ dinv, int n) {
  int i = blockIdx.x * blockDim.x + threadIdx.x;
  if (i < n) dinv[i] = rsqrtf(deg[i] + 1.0f);  // +1 = self-loop weight; always > 0
}

// Exclusive scan of cnt[N] -> offs[N] (3-kernel: per-block scan, block-sum scan, add).
__global__ void k_scan1(const int* __restrict__ cnt, int* __restrict__ offs,
                        int* __restrict__ bsum, int n) {
  __shared__ int s[256];
  int t = threadIdx.x;
  int i = blockIdx.x * 256 + t;
  int v = (i < n) ? cnt[i] : 0;
  s[t] = v;
  __syncthreads();
  for (int off = 1; off < 256; off <<= 1) {
    int x = 0;
    if (t >= off) x = s[t - off];
    __syncthreads();
    if (t >= off) s[t] += x;
    __syncthreads();
  }
  if (i < n) offs[i] = s[t] - v;
  if (t == 255) bsum[blockIdx.x] = s[255];
}

__global__ void k_scan2(const int* __restrict__ bsum, int* __restrict__ boff, int nb) {
  __shared__ int s[256];
  int t = threadIdx.x;
  int v = (t < nb) ? bsum[t] : 0;
  s[t] = v;
  __syncthreads();
  for (int off = 1; off < 256; off <<= 1) {
    int x = 0;
    if (t >= off) x = s[t - off];
    __syncthreads();
    if (t >= off) s[t] += x;
    __syncthreads();
  }
  if (t < nb) boff[t] = s[t] - v;
}

__global__ void k_scan3(int* __restrict__ offs, const int* __restrict__ boff, int n, int nE) {
  int i = blockIdx.x * 256 + threadIdx.x;
  if (i < n) offs[i] += boff[blockIdx.x];
  if (i == 0) offs[n] = nE;
}

__global__ void k_fill(const int* __restrict__ ei, const float* __restrict__ w,
                       const float* __restrict__ dinv, const int* __restrict__ offs,
                       int* __restrict__ cur, int* __restrict__ srow,
                       float* __restrict__ scoef, const int* __restrict__ flag,
                       int nE, int n) {
  int e = blockIdx.x * blockDim.x + threadIdx.x;
  if (e >= nE) return;
  int m64 = *flag;
  int r, c;
  load_edge(ei, e, nE, m64, n, r, c);
  int p = atomicAdd(&cur[c], 1);
  int idx = offs[c] + p;
  srow[idx] = r;
  scoef[idx] = dinv[r] * w[e] * dinv[c];
}

// ---------------- GEMM: Y = act(A) @ W,  A:[n,128], W:[128,128] ----------------
// ACT: 0 = identity, 1 = ELU, 2 = exact GELU
template <int ACT>
__device__ __forceinline__ float act_f(float x) {
  if (ACT == 1) return x > 0.f ? x : expm1f(x);
  if (ACT == 2) return 0.5f * x * (1.0f + erff(x * 0.70710678118654752440f));
  return x;
}

template <int ACT>
__global__ __launch_bounds__(256, 2) void k_gemm(const float* __restrict__ A,
                                                 const float* __restrict__ W,
                                                 float* __restrict__ Y, int n) {
  __shared__ float As[64 * 36];   // 64 rows x 32 k, row stride 36 (16B aligned, conflict-lite)
  __shared__ float Ws[32 * 128];  // 32 k x 128 cols
  const int tid = threadIdx.x;
  const int row0 = blockIdx.x * 64;
  const int tc = tid & 15;   // 16 col-groups x 8 cols
  const int tr = tid >> 4;   // 16 row-groups x 4 rows

  float acc[4][8];
#pragma unroll
  for (int i = 0; i < 4; ++i)
#pragma unroll
    for (int j = 0; j < 8; ++j) acc[i][j] = 0.f;

  for (int kt = 0; kt < 4; ++kt) {
    // stage A tile (activation fused; each element staged exactly once per layer)
#pragma unroll
    for (int i = 0; i < 2; ++i) {
      int idx = tid + i * 256;      // 0..511 float4s
      int r = idx >> 3;             // 8 float4 per row
      int c4 = idx & 7;
      float4 v = make_float4(0.f, 0.f, 0.f, 0.f);
      int gr = row0 + r;
      if (gr < n) v = *(const float4*)(A + (size_t)gr * D + kt * 32 + c4 * 4);
      v.x = act_f<ACT>(v.x); v.y = act_f<ACT>(v.y);
      v.z = act_f<ACT>(v.z); v.w = act_f<ACT>(v.w);
      *(float4*)(&As[r * 36 + c4 * 4]) = v;
    }
    // stage W tile
#pragma unroll
    for (int i = 0; i < 4; ++i) {
      int idx = tid + i * 256;      // 0..1023 float4s
      int r = idx >> 5;             // 32 float4 per row
      int c4 = idx & 31;
      *(float4*)(&Ws[r * 128 + c4 * 4]) =
          *(const float4*)(W + (size_t)(kt * 32 + r) * D + c4 * 4);
    }
    __syncthreads();
#pragma unroll
    for (int k = 0; k < 32; ++k) {
      float a[4];
#pragma unroll
      for (int i = 0; i < 4; ++i) a[i] = As[(tr * 4 + i) * 36 + k];
      const float4 b0 = *(const float4*)(&Ws[k * 128 + tc * 8]);
      const float4 b1 = *(const float4*)(&Ws[k * 128 + tc * 8 + 4]);
#pragma unroll
      for (int i = 0; i < 4; ++i) {
        acc[i][0] += a[i] * b0.x; acc[i][1] += a[i] * b0.y;
        acc[i][2] += a[i] * b0.z; acc[i][3] += a[i] * b0.w;
        acc[i][4] += a[i] * b1.x; acc[i][5] += a[i] * b1.y;
        acc[i][6] += a[i] * b1.z; acc[i][7] += a[i] * b1.w;
      }
    }
    __syncthreads();
  }
#pragma unroll
  for (int i = 0; i < 4; ++i) {
    int gr = row0 + tr * 4 + i;
    if (gr < n) {
      float4 o0 = make_float4(acc[i][0], acc[i][1], acc[i][2], acc[i][3]);
      float4 o1 = make_float4(acc[i][4], acc[i][5], acc[i][6], acc[i][7]);
      *(float4*)(Y + (size_t)gr * D + tc * 8) = o0;
      *(float4*)(Y + (size_t)gr * D + tc * 8 + 4) = o1;
    }
  }
}

// ---------------- aggregation: OUT[c] = dinv[c]^2*Y[c] + b + sum coef*Y[row] ----------------
__global__ __launch_bounds__(256) void k_agg(const float* __restrict__ Y,
                                             const int* __restrict__ offs,
                                             const int* __restrict__ srow,
                                             const float* __restrict__ scoef,
                                             const float* __restrict__ dinv,
                                             const float* __restrict__ bias,
                                             float* __restrict__ OUT, int n) {
  int gi = blockIdx.x * blockDim.x + threadIdx.x;
  int node = gi >> 5;   // 32 lanes per node
  int j = gi & 31;      // float4 chunk within the 128-wide row
  if (node >= n) return;
  float di = dinv[node];
  float s = di * di;
  float4 b4 = *(const float4*)(bias + j * 4);
  float4 y0 = *(const float4*)(Y + (size_t)node * D + j * 4);
  float4 acc = make_float4(b4.x + s * y0.x, b4.y + s * y0.y,
                           b4.z + s * y0.z, b4.w + s * y0.w);
  int e0 = offs[node], e1 = offs[node + 1];
  for (int e = e0; e < e1; ++e) {
    int r = srow[e];
    float cf = scoef[e];
    const float4 y = *(const float4*)(Y + (size_t)r * D + j * 4);
    acc.x += cf * y.x; acc.y += cf * y.y; acc.z += cf * y.z; acc.w += cf * y.w;
  }
  *(float4*)(OUT + (size_t)node * D + j * 4) = acc;
}

__global__ void k_prelu(float* __restrict__ h, const float* __restrict__ pw, int n4) {
  int i = blockIdx.x * blockDim.x + threadIdx.x;
  if (i >= n4) return;
  float w = *pw;
  float4 v = ((float4*)h)[i];
  v.x = v.x >= 0.f ? v.x : w * v.x;
  v.y = v.y >= 0.f ? v.y : w * v.y;
  v.z = v.z >= 0.f ? v.z : w * v.z;
  v.w = v.w >= 0.f ? v.w : w * v.w;
  ((float4*)h)[i] = v;
}

// ---------------- launch ----------------
extern "C" void kernel_launch(void* const* d_in, const int* in_sizes, int n_in,
                              void* d_out, int out_size, void* d_ws, size_t ws_size,
                              hipStream_t stream) {
  const float* x  = (const float*)d_in[0];
  const int*   ei = (const int*)d_in[1];
  const float* w  = (const float*)d_in[2];
  const float* W1 = (const float*)d_in[3];
  const float* b1 = (const float*)d_in[4];
  const float* W2 = (const float*)d_in[5];
  const float* b2 = (const float*)d_in[6];
  const float* W3 = (const float*)d_in[7];
  const float* b3 = (const float*)d_in[8];
  const float* pw = (const float*)d_in[9];
  const int N = in_sizes[0] / D;
  const int E = in_sizes[2];
  float* out = (float*)d_out;

  char* wsb = (char*)d_ws;
  size_t off = 0;
  auto alloc = [&](size_t bytes) {
    void* p = wsb + off;
    off = (off + bytes + 255) & ~(size_t)255;
    return p;
  };
  float* deg   = (float*)alloc((size_t)N * 4);
  float* dinv  = (float*)alloc((size_t)N * 4);
  int*   cnt   = (int*)alloc((size_t)N * 4);
  int*   cur   = (int*)alloc((size_t)N * 4);
  int*   offs  = (int*)alloc((size_t)(N + 1) * 4);
  int*   bsum  = (int*)alloc(256 * 4);
  int*   boff  = (int*)alloc(256 * 4);
  int*   flag  = (int*)alloc(4);
  int*   srow  = (int*)alloc((size_t)E * 4);
  float* scoef = (float*)alloc((size_t)E * 4);
  float* Y     = (float*)alloc((size_t)N * D * 4);

  const int nb = (N + 255) / 256;
  const int eb = (E + 255) / 256;

  hipLaunchKernelGGL(k_detect, dim3(1), dim3(64), 0, stream, ei, flag);
  hipLaunchKernelGGL(k_zero,   dim3(nb), dim3(256), 0, stream, deg, cnt, cur, N);
  hipLaunchKernelGGL(k_count,  dim3(eb), dim3(256), 0, stream, ei, w, deg, cnt, flag, E, N);
  hipLaunchKernelGGL(k_dinv,   dim3(nb), dim3(256), 0, stream, deg, dinv, N);
  hipLaunchKernelGGL(k_scan1,  dim3(nb), dim3(256), 0, stream, cnt, offs, bsum, N);
  hipLaunchKernelGGL(k_scan2,  dim3(1),  dim3(256), 0, stream, bsum, boff, nb);
  hipLaunchKernelGGL(k_scan3,  dim3(nb), dim3(256), 0, stream, offs, boff, N, E);
  hipLaunchKernelGGL(k_fill,   dim3(eb), dim3(256), 0, stream, ei, w, dinv, offs, cur, srow, scoef, flag, E, N);

  const int gb = (N + 63) / 64;                 // GEMM blocks (64 rows each)
  const int ab = (N * 32 + 255) / 256;          // agg blocks (8 nodes each)

  // layer 1: Y = x @ W1 ; out = agg(Y) + b1
  hipLaunchKernelGGL((k_gemm<0>), dim3(gb), dim3(256), 0, stream, x, W1, Y, N);
  hipLaunchKernelGGL(k_agg, dim3(ab), dim3(256), 0, stream, Y, offs, srow, scoef, dinv, b1, out, N);
  // layer 2: Y = elu(out) @ W2 ; out = agg(Y) + b2
  hipLaunchKernelGGL((k_gemm<1>), dim3(gb), dim3(256), 0, stream, out, W2, Y, N);
  hipLaunchKernelGGL(k_agg, dim3(ab), dim3(256), 0, stream, Y, offs, srow, scoef, dinv, b2, out, N);
  // layer 3: Y = gelu(out) @ W3 ; out = agg(Y) + b3
  hipLaunchKernelGGL((k_gemm<2>), dim3(gb), dim3(256), 0, stream, out, W3, Y, N);
  hipLaunchKernelGGL(k_agg, dim3(ab), dim3(256), 0, stream, Y, offs, srow, scoef, dinv, b3, out, N);
  // prelu in place
  const int n4 = N * D / 4;
  hipLaunchKernelGGL(k_prelu, dim3((n4 + 255) / 256), dim3(256), 0, stream, out, pw, n4);
}

// Round 2
// 381.793 us; speedup vs baseline: 1.1796x; 1.1796x over previous
//
#include <hip/hip_runtime.h>
#include <math.h>

constexpr int D = 128;

// ---------------- preprocessing ----------------

__device__ __forceinline__ int detect64(const int* __restrict__ ei) {
  // int64 little-endian edge_index => odd int32 words of first entries are 0
  int z = 0;
#pragma unroll
  for (int i = 0; i < 8; ++i) z |= ei[2 * i + 1];
  return (z == 0) ? 1 : 0;
}

__device__ __forceinline__ void load_edge(const int* __restrict__ ei, int e, int nE,
                                          int m64, int n, int& r, int& c) {
  if (m64) { r = ei[2 * (size_t)e]; c = ei[2 * ((size_t)nE + e)]; }
  else     { r = ei[(size_t)e];     c = ei[(size_t)nE + e]; }
  r = min(max(r, 0), n - 1);
  c = min(max(c, 0), n - 1);
}

__global__ void k_zero(int* __restrict__ cnt, int n) {
  int i = blockIdx.x * blockDim.x + threadIdx.x;
  if (i < n) cnt[i] = 0;
}

// One atomic per edge; record rank within destination row + decoded (r,c).
__global__ void k_pos(const int* __restrict__ ei, int* __restrict__ cnt,
                      int2* __restrict__ rc, int* __restrict__ pos, int nE, int n) {
  int e = blockIdx.x * blockDim.x + threadIdx.x;
  if (e >= nE) return;
  int m64 = detect64(ei);   // wave-uniform, cached
  int r, c;
  load_edge(ei, e, nE, m64, n, r, c);
  rc[e] = make_int2(r, c);
  pos[e] = atomicAdd(&cnt[c], 1);
}

// Exclusive scan of cnt[N] -> offs[N] (3-kernel).
__global__ void k_scan1(const int* __restrict__ cnt, int* __restrict__ offs,
                        int* __restrict__ bsum, int n) {
  __shared__ int s[256];
  int t = threadIdx.x;
  int i = blockIdx.x * 256 + t;
  int v = (i < n) ? cnt[i] : 0;
  s[t] = v;
  __syncthreads();
  for (int off = 1; off < 256; off <<= 1) {
    int x = 0;
    if (t >= off) x = s[t - off];
    __syncthreads();
    if (t >= off) s[t] += x;
    __syncthreads();
  }
  if (i < n) offs[i] = s[t] - v;
  if (t == 255) bsum[blockIdx.x] = s[255];
}

__global__ void k_scan2(const int* __restrict__ bsum, int* __restrict__ boff, int nb) {
  __shared__ int s[256];
  int t = threadIdx.x;
  int v = (t < nb) ? bsum[t] : 0;
  s[t] = v;
  __syncthreads();
  for (int off = 1; off < 256; off <<= 1) {
    int x = 0;
    if (t >= off) x = s[t - off];
    __syncthreads();
    if (t >= off) s[t] += x;
    __syncthreads();
  }
  if (t < nb) boff[t] = s[t] - v;
}

__global__ void k_scan3(int* __restrict__ offs, const int* __restrict__ boff, int n, int nE) {
  int i = blockIdx.x * 256 + threadIdx.x;
  if (i < n) offs[i] += boff[blockIdx.x];
  if (i == 0) offs[n] = nE;
}

// No atomics: idx = offs[c] + precomputed rank. ONE random 8B store per edge.
__global__ void k_fill(const int2* __restrict__ rc, const int* __restrict__ pos,
                       const float* __restrict__ w, const int* __restrict__ offs,
                       int2* __restrict__ ecf, int nE) {
  int e = blockIdx.x * blockDim.x + threadIdx.x;
  if (e >= nE) return;
  int2 p = rc[e];
  int idx = offs[p.y] + pos[e];
  ecf[idx] = make_int2(p.x, __float_as_int(w[e]));
}

// deg[c] = 1 (self loop) + sum of w over CSR row; dinv = rsqrt(deg).
__global__ void k_degdinv(const int2* __restrict__ ecf, const int* __restrict__ offs,
                          float* __restrict__ dinv, int n) {
  int i = blockIdx.x * blockDim.x + threadIdx.x;
  if (i >= n) return;
  float s = 1.0f;
  int e1 = offs[i + 1];
  for (int e = offs[i]; e < e1; ++e) s += __int_as_float(ecf[e].y);
  dinv[i] = rsqrtf(s);
}

// ---------------- GEMM: Y = act(A) @ W,  A:[n,128], W:[128,128] ----------------
template <int ACT>
__device__ __forceinline__ float act_f(float x) {
  if (ACT == 1) return x > 0.f ? x : expm1f(x);
  if (ACT == 2) return 0.5f * x * (1.0f + erff(x * 0.70710678118654752440f));
  return x;
}

template <int ACT>
__global__ __launch_bounds__(256, 2) void k_gemm(const float* __restrict__ A,
                                                 const float* __restrict__ W,
                                                 float* __restrict__ Y, int n) {
  __shared__ float As[64 * 36];
  __shared__ float Ws[32 * 128];
  const int tid = threadIdx.x;
  const int row0 = blockIdx.x * 64;
  const int tc = tid & 15;
  const int tr = tid >> 4;

  float acc[4][8];
#pragma unroll
  for (int i = 0; i < 4; ++i)
#pragma unroll
    for (int j = 0; j < 8; ++j) acc[i][j] = 0.f;

  for (int kt = 0; kt < 4; ++kt) {
#pragma unroll
    for (int i = 0; i < 2; ++i) {
      int idx = tid + i * 256;
      int r = idx >> 3;
      int c4 = idx & 7;
      float4 v = make_float4(0.f, 0.f, 0.f, 0.f);
      int gr = row0 + r;
      if (gr < n) v = *(const float4*)(A + (size_t)gr * D + kt * 32 + c4 * 4);
      v.x = act_f<ACT>(v.x); v.y = act_f<ACT>(v.y);
      v.z = act_f<ACT>(v.z); v.w = act_f<ACT>(v.w);
      *(float4*)(&As[r * 36 + c4 * 4]) = v;
    }
#pragma unroll
    for (int i = 0; i < 4; ++i) {
      int idx = tid + i * 256;
      int r = idx >> 5;
      int c4 = idx & 31;
      *(float4*)(&Ws[r * 128 + c4 * 4]) =
          *(const float4*)(W + (size_t)(kt * 32 + r) * D + c4 * 4);
    }
    __syncthreads();
#pragma unroll
    for (int k = 0; k < 32; ++k) {
      float a[4];
#pragma unroll
      for (int i = 0; i < 4; ++i) a[i] = As[(tr * 4 + i) * 36 + k];
      const float4 b0 = *(const float4*)(&Ws[k * 128 + tc * 8]);
      const float4 b1 = *(const float4*)(&Ws[k * 128 + tc * 8 + 4]);
#pragma unroll
      for (int i = 0; i < 4; ++i) {
        acc[i][0] += a[i] * b0.x; acc[i][1] += a[i] * b0.y;
        acc[i][2] += a[i] * b0.z; acc[i][3] += a[i] * b0.w;
        acc[i][4] += a[i] * b1.x; acc[i][5] += a[i] * b1.y;
        acc[i][6] += a[i] * b1.z; acc[i][7] += a[i] * b1.w;
      }
    }
    __syncthreads();
  }
#pragma unroll
  for (int i = 0; i < 4; ++i) {
    int gr = row0 + tr * 4 + i;
    if (gr < n) {
      float4 o0 = make_float4(acc[i][0], acc[i][1], acc[i][2], acc[i][3]);
      float4 o1 = make_float4(acc[i][4], acc[i][5], acc[i][6], acc[i][7]);
      *(float4*)(Y + (size_t)gr * D + tc * 8) = o0;
      *(float4*)(Y + (size_t)gr * D + tc * 8 + 4) = o1;
    }
  }
}

// -------- aggregation: OUT[c] = dc*( sum dinv[r]*w*Y[r] + dc*Y[c] ) + b --------
template <int PRELU>
__global__ __launch_bounds__(256) void k_agg(const float* __restrict__ Y,
                                             const int* __restrict__ offs,
                                             const int2* __restrict__ ecf,
                                             const float* __restrict__ dinv,
                                             const float* __restrict__ bias,
                                             const float* __restrict__ pw,
                                             float* __restrict__ OUT, int n) {
  int gi = blockIdx.x * blockDim.x + threadIdx.x;
  int node = gi >> 5;   // 32 lanes per node
  int j = gi & 31;      // float4 chunk of the 128-wide row
  if (node >= n) return;
  float dc = dinv[node];
  float4 y0 = *(const float4*)(Y + (size_t)node * D + j * 4);
  float4 acc = make_float4(dc * y0.x, dc * y0.y, dc * y0.z, dc * y0.w);
  int e0 = offs[node], e1 = offs[node + 1];
  int e = e0;
  for (; e + 1 < e1; e += 2) {   // 2-deep unroll: two independent gathers in flight
    int2 pa = ecf[e];
    int2 pb = ecf[e + 1];
    float ca = dinv[pa.x] * __int_as_float(pa.y);
    float cb = dinv[pb.x] * __int_as_float(pb.y);
    const float4 ya = *(const float4*)(Y + (size_t)pa.x * D + j * 4);
    const float4 yb = *(const float4*)(Y + (size_t)pb.x * D + j * 4);
    acc.x += ca * ya.x; acc.y += ca * ya.y; acc.z += ca * ya.z; acc.w += ca * ya.w;
    acc.x += cb * yb.x; acc.y += cb * yb.y; acc.z += cb * yb.z; acc.w += cb * yb.w;
  }
  if (e < e1) {
    int2 pa = ecf[e];
    float ca = dinv[pa.x] * __int_as_float(pa.y);
    const float4 ya = *(const float4*)(Y + (size_t)pa.x * D + j * 4);
    acc.x += ca * ya.x; acc.y += ca * ya.y; acc.z += ca * ya.z; acc.w += ca * ya.w;
  }
  float4 b4 = *(const float4*)(bias + j * 4);
  float4 o = make_float4(dc * acc.x + b4.x, dc * acc.y + b4.y,
                         dc * acc.z + b4.z, dc * acc.w + b4.w);
  if (PRELU) {
    float wv = *pw;
    o.x = o.x >= 0.f ? o.x : wv * o.x;
    o.y = o.y >= 0.f ? o.y : wv * o.y;
    o.z = o.z >= 0.f ? o.z : wv * o.z;
    o.w = o.w >= 0.f ? o.w : wv * o.w;
  }
  *(float4*)(OUT + (size_t)node * D + j * 4) = o;
}

// ---------------- launch ----------------
extern "C" void kernel_launch(void* const* d_in, const int* in_sizes, int n_in,
                              void* d_out, int out_size, void* d_ws, size_t ws_size,
                              hipStream_t stream) {
  const float* x  = (const float*)d_in[0];
  const int*   ei = (const int*)d_in[1];
  const float* w  = (const float*)d_in[2];
  const float* W1 = (const float*)d_in[3];
  const float* b1 = (const float*)d_in[4];
  const float* W2 = (const float*)d_in[5];
  const float* b2 = (const float*)d_in[6];
  const float* W3 = (const float*)d_in[7];
  const float* b3 = (const float*)d_in[8];
  const float* pw = (const float*)d_in[9];
  const int N = in_sizes[0] / D;
  const int E = in_sizes[2];
  float* out = (float*)d_out;

  char* wsb = (char*)d_ws;
  size_t off = 0;
  auto alloc = [&](size_t bytes) {
    void* p = wsb + off;
    off = (off + bytes + 255) & ~(size_t)255;
    return p;
  };
  float* dinv = (float*)alloc((size_t)N * 4);
  int*   cnt  = (int*)alloc((size_t)N * 4);
  int*   offs = (int*)alloc((size_t)(N + 1) * 4);
  int*   bsum = (int*)alloc(256 * 4);
  int*   boff = (int*)alloc(256 * 4);
  int2*  ecf  = (int2*)alloc((size_t)E * 8);
  float* Y    = (float*)alloc((size_t)N * D * 4);
  // transient buffers aliased into Y (dead before first GEMM writes Y)
  int2*  rc   = (int2*)Y;                         // E*8 bytes
  int*   pos  = (int*)((char*)Y + (size_t)E * 8); // E*4 bytes  (12B/edge << N*D*4)

  const int nb = (N + 255) / 256;
  const int eb = (E + 255) / 256;

  hipLaunchKernelGGL(k_zero,    dim3(nb), dim3(256), 0, stream, cnt, N);
  hipLaunchKernelGGL(k_pos,     dim3(eb), dim3(256), 0, stream, ei, cnt, rc, pos, E, N);
  hipLaunchKernelGGL(k_scan1,   dim3(nb), dim3(256), 0, stream, cnt, offs, bsum, N);
  hipLaunchKernelGGL(k_scan2,   dim3(1),  dim3(256), 0, stream, bsum, boff, nb);
  hipLaunchKernelGGL(k_scan3,   dim3(nb), dim3(256), 0, stream, offs, boff, N, E);
  hipLaunchKernelGGL(k_fill,    dim3(eb), dim3(256), 0, stream, rc, pos, w, offs, ecf, E);
  hipLaunchKernelGGL(k_degdinv, dim3(nb), dim3(256), 0, stream, ecf, offs, dinv, N);

  const int gb = (N + 63) / 64;
  const int ab = (N * 32 + 255) / 256;

  hipLaunchKernelGGL((k_gemm<0>), dim3(gb), dim3(256), 0, stream, x, W1, Y, N);
  hipLaunchKernelGGL((k_agg<0>),  dim3(ab), dim3(256), 0, stream, Y, offs, ecf, dinv, b1, pw, out, N);
  hipLaunchKernelGGL((k_gemm<1>), dim3(gb), dim3(256), 0, stream, out, W2, Y, N);
  hipLaunchKernelGGL((k_agg<0>),  dim3(ab), dim3(256), 0, stream, Y, offs, ecf, dinv, b2, pw, out, N);
  hipLaunchKernelGGL((k_gemm<2>), dim3(gb), dim3(256), 0, stream, out, W3, Y, N);
  hipLaunchKernelGGL((k_agg<1>),  dim3(ab), dim3(256), 0, stream, Y, offs, ecf, dinv, b3, pw, out, N);
}

// Round 3
// 324.449 us; speedup vs baseline: 1.3881x; 1.1767x over previous
//
#include <hip/hip_runtime.h>
#include <hip/hip_fp16.h>
#include <math.h>

constexpr int D = 128;

struct __align__(16) H8 { __half2 h[4]; };
struct __align__(8)  H4 { __half2 a, b; };

// ---------------- preprocessing ----------------

__device__ __forceinline__ int detect64(const int* __restrict__ ei) {
  int z = 0;
#pragma unroll
  for (int i = 0; i < 8; ++i) z |= ei[2 * i + 1];
  return (z == 0) ? 1 : 0;
}

__device__ __forceinline__ void load_edge(const int* __restrict__ ei, int e, int nE,
                                          int m64, int n, int& r, int& c) {
  if (m64) { r = ei[2 * (size_t)e]; c = ei[2 * ((size_t)nE + e)]; }
  else     { r = ei[(size_t)e];     c = ei[(size_t)nE + e]; }
  r = min(max(r, 0), n - 1);
  c = min(max(c, 0), n - 1);
}

__global__ void k_zero(int* __restrict__ cnt, int n) {
  int i = blockIdx.x * blockDim.x + threadIdx.x;
  if (i < n) cnt[i] = 0;
}

__global__ void k_pos(const int* __restrict__ ei, int* __restrict__ cnt,
                      int2* __restrict__ rc, int* __restrict__ pos, int nE, int n) {
  int e = blockIdx.x * blockDim.x + threadIdx.x;
  if (e >= nE) return;
  int m64 = detect64(ei);
  int r, c;
  load_edge(ei, e, nE, m64, n, r, c);
  rc[e] = make_int2(r, c);
  pos[e] = atomicAdd(&cnt[c], 1);
}

__global__ void k_scan1(const int* __restrict__ cnt, int* __restrict__ offs,
                        int* __restrict__ bsum, int n) {
  __shared__ int s[256];
  int t = threadIdx.x;
  int i = blockIdx.x * 256 + t;
  int v = (i < n) ? cnt[i] : 0;
  s[t] = v;
  __syncthreads();
  for (int off = 1; off < 256; off <<= 1) {
    int x = 0;
    if (t >= off) x = s[t - off];
    __syncthreads();
    if (t >= off) s[t] += x;
    __syncthreads();
  }
  if (i < n) offs[i] = s[t] - v;
  if (t == 255) bsum[blockIdx.x] = s[255];
}

__global__ void k_scan2(const int* __restrict__ bsum, int* __restrict__ boff, int nb) {
  __shared__ int s[256];
  int t = threadIdx.x;
  int v = (t < nb) ? bsum[t] : 0;
  s[t] = v;
  __syncthreads();
  for (int off = 1; off < 256; off <<= 1) {
    int x = 0;
    if (t >= off) x = s[t - off];
    __syncthreads();
    if (t >= off) s[t] += x;
    __syncthreads();
  }
  if (t < nb) boff[t] = s[t] - v;
}

__global__ void k_scan3(int* __restrict__ offs, const int* __restrict__ boff, int n, int nE) {
  int i = blockIdx.x * 256 + threadIdx.x;
  if (i < n) offs[i] += boff[blockIdx.x];
  if (i == 0) offs[n] = nE;
}

__global__ void k_fill(const int2* __restrict__ rc, const int* __restrict__ pos,
                       const float* __restrict__ w, const int* __restrict__ offs,
                       int2* __restrict__ ecf, int nE) {
  int e = blockIdx.x * blockDim.x + threadIdx.x;
  if (e >= nE) return;
  int2 p = rc[e];
  int idx = offs[p.y] + pos[e];
  ecf[idx] = make_int2(p.x, __float_as_int(w[e]));
}

__global__ void k_degdinv(const int2* __restrict__ ecf, const int* __restrict__ offs,
                          float* __restrict__ dinv, int n) {
  int i = blockIdx.x * blockDim.x + threadIdx.x;
  if (i >= n) return;
  float s = 1.0f;
  int e1 = offs[i + 1];
  for (int e = offs[i]; e < e1; ++e) s += __int_as_float(ecf[e].y);
  dinv[i] = rsqrtf(s);
}

// ---------------- GEMM: Yh = half( act(A) @ W ),  A:[n,128] fp32, W:[128,128] ----------------
template <int ACT>
__device__ __forceinline__ float act_f(float x) {
  if (ACT == 1) return x > 0.f ? x : expm1f(x);
  if (ACT == 2) return 0.5f * x * (1.0f + erff(x * 0.70710678118654752440f));
  return x;
}

// 128 rows x 128 cols per block, 256 threads, thread = 8 rows x 8 cols.
// As stride 33: a-reads and staging writes <=2-way banked (free).
// Col split {tc*4, tc*4+64}: Ws b128 reads 2-way (free).
template <int ACT>
__global__ __launch_bounds__(256, 2) void k_gemm(const float* __restrict__ A,
                                                 const float* __restrict__ W,
                                                 __half* __restrict__ Y, int n) {
  __shared__ float As[128 * 33];
  __shared__ float Ws[32 * 128];
  const int tid = threadIdx.x;
  const int row0 = blockIdx.x * 128;
  const int tc = tid & 15;   // 16 col groups
  const int tr = tid >> 4;   // 16 row groups x 8 rows

  float acc[8][8];
#pragma unroll
  for (int i = 0; i < 8; ++i)
#pragma unroll
    for (int j = 0; j < 8; ++j) acc[i][j] = 0.f;

  for (int kt = 0; kt < 4; ++kt) {
    // stage A tile (128 rows x 32 k), activation fused
#pragma unroll
    for (int i = 0; i < 4; ++i) {
      int idx = tid + i * 256;      // 0..1023 float4s
      int r = idx >> 3;             // 0..127
      int c4 = idx & 7;             // float4 within 32-k chunk
      float4 v = make_float4(0.f, 0.f, 0.f, 0.f);
      int gr = row0 + r;
      if (gr < n) v = *(const float4*)(A + (size_t)gr * D + kt * 32 + c4 * 4);
      v.x = act_f<ACT>(v.x); v.y = act_f<ACT>(v.y);
      v.z = act_f<ACT>(v.z); v.w = act_f<ACT>(v.w);
      As[r * 33 + c4 * 4 + 0] = v.x;
      As[r * 33 + c4 * 4 + 1] = v.y;
      As[r * 33 + c4 * 4 + 2] = v.z;
      As[r * 33 + c4 * 4 + 3] = v.w;
    }
    // stage W tile (32 k x 128 cols)
#pragma unroll
    for (int i = 0; i < 4; ++i) {
      int idx = tid + i * 256;
      int r = idx >> 5;
      int c4 = idx & 31;
      *(float4*)(&Ws[r * 128 + c4 * 4]) =
          *(const float4*)(W + (size_t)(kt * 32 + r) * D + c4 * 4);
    }
    __syncthreads();
#pragma unroll
    for (int k = 0; k < 32; ++k) {
      float a[8];
#pragma unroll
      for (int i = 0; i < 8; ++i) a[i] = As[(tr * 8 + i) * 33 + k];
      const float4 b0 = *(const float4*)(&Ws[k * 128 + tc * 4]);
      const float4 b1 = *(const float4*)(&Ws[k * 128 + tc * 4 + 64]);
#pragma unroll
      for (int i = 0; i < 8; ++i) {
        acc[i][0] += a[i] * b0.x; acc[i][1] += a[i] * b0.y;
        acc[i][2] += a[i] * b0.z; acc[i][3] += a[i] * b0.w;
        acc[i][4] += a[i] * b1.x; acc[i][5] += a[i] * b1.y;
        acc[i][6] += a[i] * b1.z; acc[i][7] += a[i] * b1.w;
      }
    }
    __syncthreads();
  }
#pragma unroll
  for (int i = 0; i < 8; ++i) {
    int gr = row0 + tr * 8 + i;
    if (gr < n) {
      H4 lo, hi;
      lo.a = __floats2half2_rn(acc[i][0], acc[i][1]);
      lo.b = __floats2half2_rn(acc[i][2], acc[i][3]);
      hi.a = __floats2half2_rn(acc[i][4], acc[i][5]);
      hi.b = __floats2half2_rn(acc[i][6], acc[i][7]);
      *(H4*)(Y + (size_t)gr * D + tc * 4) = lo;
      *(H4*)(Y + (size_t)gr * D + tc * 4 + 64) = hi;
    }
  }
}

// -------- aggregation: OUT[c] = dc*( sum dinv[r]*w*Yh[r] + dc*Yh[c] ) + b --------
__device__ __forceinline__ void fmacc8(float* acc, float c, const H8& y) {
  float2 f;
  f = __half22float2(y.h[0]); acc[0] += c * f.x; acc[1] += c * f.y;
  f = __half22float2(y.h[1]); acc[2] += c * f.x; acc[3] += c * f.y;
  f = __half22float2(y.h[2]); acc[4] += c * f.x; acc[5] += c * f.y;
  f = __half22float2(y.h[3]); acc[6] += c * f.x; acc[7] += c * f.y;
}

template <int PRELU>
__global__ __launch_bounds__(256) void k_agg(const __half* __restrict__ Y,
                                             const int* __restrict__ offs,
                                             const int2* __restrict__ ecf,
                                             const float* __restrict__ dinv,
                                             const float* __restrict__ bias,
                                             const float* __restrict__ pw,
                                             float* __restrict__ OUT, int n) {
  int gi = blockIdx.x * blockDim.x + threadIdx.x;
  int node = gi >> 4;   // 16 lanes per node
  int j = gi & 15;      // 8-half chunk (16B) of the 128-wide row
  if (node >= n) return;
  float dc = dinv[node];
  float acc[8] = {0.f, 0.f, 0.f, 0.f, 0.f, 0.f, 0.f, 0.f};
  {
    H8 ys = *(const H8*)(Y + (size_t)node * D + j * 8);
    fmacc8(acc, dc, ys);
  }
  int e0 = offs[node], e1 = offs[node + 1];
  int e = e0;
  for (; e + 4 <= e1; e += 4) {   // 4 independent gathers in flight
    int2 p0 = ecf[e], p1 = ecf[e + 1], p2 = ecf[e + 2], p3 = ecf[e + 3];
    float c0 = dinv[p0.x] * __int_as_float(p0.y);
    float c1 = dinv[p1.x] * __int_as_float(p1.y);
    float c2 = dinv[p2.x] * __int_as_float(p2.y);
    float c3 = dinv[p3.x] * __int_as_float(p3.y);
    H8 y0 = *(const H8*)(Y + (size_t)p0.x * D + j * 8);
    H8 y1 = *(const H8*)(Y + (size_t)p1.x * D + j * 8);
    H8 y2 = *(const H8*)(Y + (size_t)p2.x * D + j * 8);
    H8 y3 = *(const H8*)(Y + (size_t)p3.x * D + j * 8);
    fmacc8(acc, c0, y0);
    fmacc8(acc, c1, y1);
    fmacc8(acc, c2, y2);
    fmacc8(acc, c3, y3);
  }
  for (; e < e1; ++e) {
    int2 p = ecf[e];
    float c = dinv[p.x] * __int_as_float(p.y);
    H8 y = *(const H8*)(Y + (size_t)p.x * D + j * 8);
    fmacc8(acc, c, y);
  }
  float4 b0 = *(const float4*)(bias + j * 8);
  float4 b1 = *(const float4*)(bias + j * 8 + 4);
  float o[8];
  o[0] = dc * acc[0] + b0.x; o[1] = dc * acc[1] + b0.y;
  o[2] = dc * acc[2] + b0.z; o[3] = dc * acc[3] + b0.w;
  o[4] = dc * acc[4] + b1.x; o[5] = dc * acc[5] + b1.y;
  o[6] = dc * acc[6] + b1.z; o[7] = dc * acc[7] + b1.w;
  if (PRELU) {
    float wv = *pw;
#pragma unroll
    for (int i = 0; i < 8; ++i) o[i] = o[i] >= 0.f ? o[i] : wv * o[i];
  }
  *(float4*)(OUT + (size_t)node * D + j * 8)     = make_float4(o[0], o[1], o[2], o[3]);
  *(float4*)(OUT + (size_t)node * D + j * 8 + 4) = make_float4(o[4], o[5], o[6], o[7]);
}

// ---------------- launch ----------------
extern "C" void kernel_launch(void* const* d_in, const int* in_sizes, int n_in,
                              void* d_out, int out_size, void* d_ws, size_t ws_size,
                              hipStream_t stream) {
  const float* x  = (const float*)d_in[0];
  const int*   ei = (const int*)d_in[1];
  const float* w  = (const float*)d_in[2];
  const float* W1 = (const float*)d_in[3];
  const float* b1 = (const float*)d_in[4];
  const float* W2 = (const float*)d_in[5];
  const float* b2 = (const float*)d_in[6];
  const float* W3 = (const float*)d_in[7];
  const float* b3 = (const float*)d_in[8];
  const float* pw = (const float*)d_in[9];
  const int N = in_sizes[0] / D;
  const int E = in_sizes[2];
  float* out = (float*)d_out;

  char* wsb = (char*)d_ws;
  size_t off = 0;
  auto alloc = [&](size_t bytes) {
    void* p = wsb + off;
    off = (off + bytes + 255) & ~(size_t)255;
    return p;
  };
  float*  dinv = (float*)alloc((size_t)N * 4);
  int*    cnt  = (int*)alloc((size_t)N * 4);
  int*    offs = (int*)alloc((size_t)(N + 1) * 4);
  int*    bsum = (int*)alloc(256 * 4);
  int*    boff = (int*)alloc(256 * 4);
  int2*   ecf  = (int2*)alloc((size_t)E * 8);
  __half* Y    = (__half*)alloc((size_t)N * D * 2);
  // transient buffers aliased into Y (dead before first GEMM writes Y): 12B/edge < N*D*2
  int2*   rc   = (int2*)Y;
  int*    pos  = (int*)((char*)Y + (size_t)E * 8);

  const int nb = (N + 255) / 256;
  const int eb = (E + 255) / 256;

  hipLaunchKernelGGL(k_zero,    dim3(nb), dim3(256), 0, stream, cnt, N);
  hipLaunchKernelGGL(k_pos,     dim3(eb), dim3(256), 0, stream, ei, cnt, rc, pos, E, N);
  hipLaunchKernelGGL(k_scan1,   dim3(nb), dim3(256), 0, stream, cnt, offs, bsum, N);
  hipLaunchKernelGGL(k_scan2,   dim3(1),  dim3(256), 0, stream, bsum, boff, nb);
  hipLaunchKernelGGL(k_scan3,   dim3(nb), dim3(256), 0, stream, offs, boff, N, E);
  hipLaunchKernelGGL(k_fill,    dim3(eb), dim3(256), 0, stream, rc, pos, w, offs, ecf, E);
  hipLaunchKernelGGL(k_degdinv, dim3(nb), dim3(256), 0, stream, ecf, offs, dinv, N);

  const int gb = (N + 127) / 128;
  const int ab = (N * 16 + 255) / 256;

  hipLaunchKernelGGL((k_gemm<0>), dim3(gb), dim3(256), 0, stream, x, W1, Y, N);
  hipLaunchKernelGGL((k_agg<0>),  dim3(ab), dim3(256), 0, stream, Y, offs, ecf, dinv, b1, pw, out, N);
  hipLaunchKernelGGL((k_gemm<1>), dim3(gb), dim3(256), 0, stream, out, W2, Y, N);
  hipLaunchKernelGGL((k_agg<0>),  dim3(ab), dim3(256), 0, stream, Y, offs, ecf, dinv, b2, pw, out, N);
  hipLaunchKernelGGL((k_gemm<2>), dim3(gb), dim3(256), 0, stream, out, W3, Y, N);
  hipLaunchKernelGGL((k_agg<1>),  dim3(ab), dim3(256), 0, stream, Y, offs, ecf, dinv, b3, pw, out, N);
}

// Round 4
// 323.461 us; speedup vs baseline: 1.3924x; 1.0031x over previous
//
#include <hip/hip_runtime.h>
#include <hip/hip_fp16.h>
#include <math.h>

constexpr int D = 128;

struct __align__(16) H8 { __half2 h[4]; };
struct __align__(8)  H4 { __half2 a, b; };

// ---------------- preprocessing ----------------

__device__ __forceinline__ int detect64(const int* __restrict__ ei) {
  int z = 0;
#pragma unroll
  for (int i = 0; i < 8; ++i) z |= ei[2 * i + 1];
  return (z == 0) ? 1 : 0;
}

__device__ __forceinline__ void load_edge(const int* __restrict__ ei, int e, int nE,
                                          int m64, int n, int& r, int& c) {
  if (m64) { r = ei[2 * (size_t)e]; c = ei[2 * ((size_t)nE + e)]; }
  else     { r = ei[(size_t)e];     c = ei[(size_t)nE + e]; }
  r = min(max(r, 0), n - 1);
  c = min(max(c, 0), n - 1);
}

__global__ void k_zero(int* __restrict__ cnt, int n) {
  int i = blockIdx.x * blockDim.x + threadIdx.x;
  if (i < n) cnt[i] = 0;
}

__global__ void k_pos(const int* __restrict__ ei, int* __restrict__ cnt,
                      int2* __restrict__ rc, int* __restrict__ pos, int nE, int n) {
  int e = blockIdx.x * blockDim.x + threadIdx.x;
  if (e >= nE) return;
  int m64 = detect64(ei);
  int r, c;
  load_edge(ei, e, nE, m64, n, r, c);
  rc[e] = make_int2(r, c);
  pos[e] = atomicAdd(&cnt[c], 1);
}

__global__ void k_scan1(const int* __restrict__ cnt, int* __restrict__ offs,
                        int* __restrict__ bsum, int n) {
  __shared__ int s[256];
  int t = threadIdx.x;
  int i = blockIdx.x * 256 + t;
  int v = (i < n) ? cnt[i] : 0;
  s[t] = v;
  __syncthreads();
  for (int off = 1; off < 256; off <<= 1) {
    int x = 0;
    if (t >= off) x = s[t - off];
    __syncthreads();
    if (t >= off) s[t] += x;
    __syncthreads();
  }
  if (i < n) offs[i] = s[t] - v;
  if (t == 255) bsum[blockIdx.x] = s[255];
}

__global__ void k_scan2(const int* __restrict__ bsum, int* __restrict__ boff, int nb) {
  __shared__ int s[256];
  int t = threadIdx.x;
  int v = (t < nb) ? bsum[t] : 0;
  s[t] = v;
  __syncthreads();
  for (int off = 1; off < 256; off <<= 1) {
    int x = 0;
    if (t >= off) x = s[t - off];
    __syncthreads();
    if (t >= off) s[t] += x;
    __syncthreads();
  }
  if (t < nb) boff[t] = s[t] - v;
}

__global__ void k_scan3(int* __restrict__ offs, const int* __restrict__ boff, int n, int nE) {
  int i = blockIdx.x * 256 + threadIdx.x;
  if (i < n) offs[i] += boff[blockIdx.x];
  if (i == 0) offs[n] = nE;
}

__global__ void k_fill(const int2* __restrict__ rc, const int* __restrict__ pos,
                       const float* __restrict__ w, const int* __restrict__ offs,
                       int2* __restrict__ ecf, int nE) {
  int e = blockIdx.x * blockDim.x + threadIdx.x;
  if (e >= nE) return;
  int2 p = rc[e];
  int idx = offs[p.y] + pos[e];
  ecf[idx] = make_int2(p.x, __float_as_int(w[e]));
}

__global__ void k_degdinv(const int2* __restrict__ ecf, const int* __restrict__ offs,
                          float* __restrict__ dinv, int n) {
  int i = blockIdx.x * blockDim.x + threadIdx.x;
  if (i >= n) return;
  float s = 1.0f;
  int e1 = offs[i + 1];
  for (int e = offs[i]; e < e1; ++e) s += __int_as_float(ecf[e].y);
  dinv[i] = rsqrtf(s);
}

// ---------------- GEMM: Yh = half( act(A) @ W ),  A:[n,128] (fp32 or fp16) ----------------
template <int ACT>
__device__ __forceinline__ float act_f(float x) {
  if (ACT == 1) return x > 0.f ? x : expm1f(x);
  if (ACT == 2) return 0.5f * x * (1.0f + erff(x * 0.70710678118654752440f));
  return x;
}

template <int ACT, typename AT>
__global__ __launch_bounds__(256, 2) void k_gemm(const AT* __restrict__ A,
                                                 const float* __restrict__ W,
                                                 __half* __restrict__ Y, int n) {
  __shared__ float As[128 * 33];
  __shared__ float Ws[32 * 128];
  const int tid = threadIdx.x;
  const int row0 = blockIdx.x * 128;
  const int tc = tid & 15;
  const int tr = tid >> 4;

  float acc[8][8];
#pragma unroll
  for (int i = 0; i < 8; ++i)
#pragma unroll
    for (int j = 0; j < 8; ++j) acc[i][j] = 0.f;

  for (int kt = 0; kt < 4; ++kt) {
    // stage A tile (128 rows x 32 k), activation fused
    if constexpr (sizeof(AT) == 4) {
#pragma unroll
      for (int i = 0; i < 4; ++i) {
        int idx = tid + i * 256;      // 0..1023 float4s
        int r = idx >> 3;
        int c4 = idx & 7;
        float4 v = make_float4(0.f, 0.f, 0.f, 0.f);
        int gr = row0 + r;
        if (gr < n) v = *(const float4*)((const float*)A + (size_t)gr * D + kt * 32 + c4 * 4);
        As[r * 33 + c4 * 4 + 0] = act_f<ACT>(v.x);
        As[r * 33 + c4 * 4 + 1] = act_f<ACT>(v.y);
        As[r * 33 + c4 * 4 + 2] = act_f<ACT>(v.z);
        As[r * 33 + c4 * 4 + 3] = act_f<ACT>(v.w);
      }
    } else {
#pragma unroll
      for (int i = 0; i < 2; ++i) {
        int idx = tid + i * 256;      // 0..511 H8s
        int r = idx >> 2;
        int c8 = idx & 3;
        float f[8] = {0.f, 0.f, 0.f, 0.f, 0.f, 0.f, 0.f, 0.f};
        int gr = row0 + r;
        if (gr < n) {
          H8 v = *(const H8*)((const __half*)A + (size_t)gr * D + kt * 32 + c8 * 8);
#pragma unroll
          for (int t = 0; t < 4; ++t) {
            float2 p = __half22float2(v.h[t]);
            f[2 * t] = p.x; f[2 * t + 1] = p.y;
          }
        }
#pragma unroll
        for (int t = 0; t < 8; ++t)
          As[r * 33 + c8 * 8 + t] = act_f<ACT>(f[t]);
      }
    }
    // stage W tile (32 k x 128 cols)
#pragma unroll
    for (int i = 0; i < 4; ++i) {
      int idx = tid + i * 256;
      int r = idx >> 5;
      int c4 = idx & 31;
      *(float4*)(&Ws[r * 128 + c4 * 4]) =
          *(const float4*)(W + (size_t)(kt * 32 + r) * D + c4 * 4);
    }
    __syncthreads();
#pragma unroll
    for (int k = 0; k < 32; ++k) {
      float a[8];
#pragma unroll
      for (int i = 0; i < 8; ++i) a[i] = As[(tr * 8 + i) * 33 + k];
      const float4 b0 = *(const float4*)(&Ws[k * 128 + tc * 4]);
      const float4 b1 = *(const float4*)(&Ws[k * 128 + tc * 4 + 64]);
#pragma unroll
      for (int i = 0; i < 8; ++i) {
        acc[i][0] += a[i] * b0.x; acc[i][1] += a[i] * b0.y;
        acc[i][2] += a[i] * b0.z; acc[i][3] += a[i] * b0.w;
        acc[i][4] += a[i] * b1.x; acc[i][5] += a[i] * b1.y;
        acc[i][6] += a[i] * b1.z; acc[i][7] += a[i] * b1.w;
      }
    }
    __syncthreads();
  }
#pragma unroll
  for (int i = 0; i < 8; ++i) {
    int gr = row0 + tr * 8 + i;
    if (gr < n) {
      H4 lo, hi;
      lo.a = __floats2half2_rn(acc[i][0], acc[i][1]);
      lo.b = __floats2half2_rn(acc[i][2], acc[i][3]);
      hi.a = __floats2half2_rn(acc[i][4], acc[i][5]);
      hi.b = __floats2half2_rn(acc[i][6], acc[i][7]);
      *(H4*)(Y + (size_t)gr * D + tc * 4) = lo;
      *(H4*)(Y + (size_t)gr * D + tc * 4 + 64) = hi;
    }
  }
}

// -------- aggregation: OUT[c] = dc*( sum dinv[r]*w*Yh[r] + dc*Yh[c] ) + b --------
// 32 lanes per node: 2 edge-half-groups x 16 j-lanes (16B of the row each).
__device__ __forceinline__ void fmacc8(float* acc, float c, const H8& y) {
  float2 f;
  f = __half22float2(y.h[0]); acc[0] += c * f.x; acc[1] += c * f.y;
  f = __half22float2(y.h[1]); acc[2] += c * f.x; acc[3] += c * f.y;
  f = __half22float2(y.h[2]); acc[4] += c * f.x; acc[5] += c * f.y;
  f = __half22float2(y.h[3]); acc[6] += c * f.x; acc[7] += c * f.y;
}

template <int PRELU, typename OutT>
__global__ __launch_bounds__(256) void k_agg(const __half* __restrict__ Y,
                                             const int* __restrict__ offs,
                                             const int2* __restrict__ ecf,
                                             const float* __restrict__ dinv,
                                             const float* __restrict__ bias,
                                             const float* __restrict__ pw,
                                             OutT* __restrict__ OUT, int n) {
  int gi = blockIdx.x * blockDim.x + threadIdx.x;
  int node = gi >> 5;          // 32 lanes per node
  int sub = (gi >> 4) & 1;     // edge half-group
  int j = gi & 15;             // 8-half chunk (16B) of the 128-wide row
  if (node >= n) return;
  float dc = dinv[node];
  float acc[8] = {0.f, 0.f, 0.f, 0.f, 0.f, 0.f, 0.f, 0.f};
  if (sub == 0) {
    H8 ys = *(const H8*)(Y + (size_t)node * D + j * 8);
    fmacc8(acc, dc, ys);
  }
  int e0 = offs[node], e1 = offs[node + 1];
  int e = e0 + sub;
  for (; e + 6 < e1; e += 8) {   // this sub handles e, e+2, e+4, e+6
    int2 p0 = ecf[e], p1 = ecf[e + 2], p2 = ecf[e + 4], p3 = ecf[e + 6];
    float c0 = dinv[p0.x] * __int_as_float(p0.y);
    float c1 = dinv[p1.x] * __int_as_float(p1.y);
    float c2 = dinv[p2.x] * __int_as_float(p2.y);
    float c3 = dinv[p3.x] * __int_as_float(p3.y);
    H8 y0 = *(const H8*)(Y + (size_t)p0.x * D + j * 8);
    H8 y1 = *(const H8*)(Y + (size_t)p1.x * D + j * 8);
    H8 y2 = *(const H8*)(Y + (size_t)p2.x * D + j * 8);
    H8 y3 = *(const H8*)(Y + (size_t)p3.x * D + j * 8);
    fmacc8(acc, c0, y0);
    fmacc8(acc, c1, y1);
    fmacc8(acc, c2, y2);
    fmacc8(acc, c3, y3);
  }
  for (; e < e1; e += 2) {
    int2 p = ecf[e];
    float c = dinv[p.x] * __int_as_float(p.y);
    H8 y = *(const H8*)(Y + (size_t)p.x * D + j * 8);
    fmacc8(acc, c, y);
  }
  // combine the two halves (xor lane 16 within the 32-lane node group)
#pragma unroll
  for (int i = 0; i < 8; ++i) acc[i] += __shfl_xor(acc[i], 16, 64);
  // each sub writes its own 16B: elements j*8 + sub*4 .. +3
  float4 b4 = *(const float4*)(bias + j * 8 + sub * 4);
  float o[4];
  o[0] = dc * acc[sub * 4 + 0] + b4.x;
  o[1] = dc * acc[sub * 4 + 1] + b4.y;
  o[2] = dc * acc[sub * 4 + 2] + b4.z;
  o[3] = dc * acc[sub * 4 + 3] + b4.w;
  if (PRELU) {
    float wv = *pw;
#pragma unroll
    for (int i = 0; i < 4; ++i) o[i] = o[i] >= 0.f ? o[i] : wv * o[i];
  }
  if constexpr (sizeof(OutT) == 4) {
    *(float4*)((float*)OUT + (size_t)node * D + j * 8 + sub * 4) =
        make_float4(o[0], o[1], o[2], o[3]);
  } else {
    H4 hv;
    hv.a = __floats2half2_rn(o[0], o[1]);
    hv.b = __floats2half2_rn(o[2], o[3]);
    *(H4*)((__half*)OUT + (size_t)node * D + j * 8 + sub * 4) = hv;
  }
}

// ---------------- launch ----------------
extern "C" void kernel_launch(void* const* d_in, const int* in_sizes, int n_in,
                              void* d_out, int out_size, void* d_ws, size_t ws_size,
                              hipStream_t stream) {
  const float* x  = (const float*)d_in[0];
  const int*   ei = (const int*)d_in[1];
  const float* w  = (const float*)d_in[2];
  const float* W1 = (const float*)d_in[3];
  const float* b1 = (const float*)d_in[4];
  const float* W2 = (const float*)d_in[5];
  const float* b2 = (const float*)d_in[6];
  const float* W3 = (const float*)d_in[7];
  const float* b3 = (const float*)d_in[8];
  const float* pw = (const float*)d_in[9];
  const int N = in_sizes[0] / D;
  const int E = in_sizes[2];
  float* out = (float*)d_out;

  char* wsb = (char*)d_ws;
  size_t off = 0;
  auto alloc = [&](size_t bytes) {
    void* p = wsb + off;
    off = (off + bytes + 255) & ~(size_t)255;
    return p;
  };
  float*  dinv = (float*)alloc((size_t)N * 4);
  int*    cnt  = (int*)alloc((size_t)N * 4);
  int*    offs = (int*)alloc((size_t)(N + 1) * 4);
  int*    bsum = (int*)alloc(256 * 4);
  int*    boff = (int*)alloc(256 * 4);
  int2*   ecf  = (int2*)alloc((size_t)E * 8);
  __half* Y    = (__half*)alloc((size_t)N * D * 2);
  __half* h    = (__half*)alloc((size_t)N * D * 2);   // fp16 inter-layer activations
  // transient buffers aliased into Y (dead before first GEMM writes Y): 12B/edge < N*D*2
  int2*   rc   = (int2*)Y;
  int*    pos  = (int*)((char*)Y + (size_t)E * 8);

  const int nb = (N + 255) / 256;
  const int eb = (E + 255) / 256;

  hipLaunchKernelGGL(k_zero,    dim3(nb), dim3(256), 0, stream, cnt, N);
  hipLaunchKernelGGL(k_pos,     dim3(eb), dim3(256), 0, stream, ei, cnt, rc, pos, E, N);
  hipLaunchKernelGGL(k_scan1,   dim3(nb), dim3(256), 0, stream, cnt, offs, bsum, N);
  hipLaunchKernelGGL(k_scan2,   dim3(1),  dim3(256), 0, stream, bsum, boff, nb);
  hipLaunchKernelGGL(k_scan3,   dim3(nb), dim3(256), 0, stream, offs, boff, N, E);
  hipLaunchKernelGGL(k_fill,    dim3(eb), dim3(256), 0, stream, rc, pos, w, offs, ecf, E);
  hipLaunchKernelGGL(k_degdinv, dim3(nb), dim3(256), 0, stream, ecf, offs, dinv, N);

  const int gb = (N + 127) / 128;
  const int ab = (N * 32 + 255) / 256;

  hipLaunchKernelGGL((k_gemm<0, float>),  dim3(gb), dim3(256), 0, stream, x, W1, Y, N);
  hipLaunchKernelGGL((k_agg<0, __half>),  dim3(ab), dim3(256), 0, stream, Y, offs, ecf, dinv, b1, pw, h, N);
  hipLaunchKernelGGL((k_gemm<1, __half>), dim3(gb), dim3(256), 0, stream, h, W2, Y, N);
  hipLaunchKernelGGL((k_agg<0, __half>),  dim3(ab), dim3(256), 0, stream, Y, offs, ecf, dinv, b2, pw, h, N);
  hipLaunchKernelGGL((k_gemm<2, __half>), dim3(gb), dim3(256), 0, stream, h, W3, Y, N);
  hipLaunchKernelGGL((k_agg<1, float>),   dim3(ab), dim3(256), 0, stream, Y, offs, ecf, dinv, b3, pw, out, N);
}